// Round 17
// baseline (130.237 us; speedup 1.0000x reference)
//
#include <hip/hip_runtime.h>
#include <hip/hip_bf16.h>
#include <stdint.h>

#define HID 1024
#define BLKDIM 128
#define BKT 32              // K-tile depth
#define NKT (HID / BKT)     // 32 K-tiles

using short8 = __attribute__((ext_vector_type(8))) short;
using f32x4  = __attribute__((ext_vector_type(4))) float;
using f32x4v = __attribute__((ext_vector_type(4))) float;

__device__ __forceinline__ uint32_t bfround(float f) {
    uint32_t u = __builtin_bit_cast(uint32_t, f);
    return (u + 0x7FFFu + ((u >> 16) & 1u)) >> 16;   // RNE to bf16
}

__device__ __forceinline__ void gld16(const ushort* g, const ushort* lds_base) {
    __builtin_amdgcn_global_load_lds(
        (const __attribute__((address_space(1))) void*)g,
        (__attribute__((address_space(3))) void*)lds_base, 16, 0, 0);
}
__device__ __forceinline__ void gld16f(const float* g, const float* lds_base) {
    __builtin_amdgcn_global_load_lds(
        (const __attribute__((address_space(1))) void*)g,
        (__attribute__((address_space(3))) void*)lds_base, 16, 0, 0);
}

// ---------------- pre-pass: x-only fp32->bf16 cvt + schedule build in block 0 ----------------
__global__ __launch_bounds__(256)
void cvt_sched_kernel(const float* __restrict__ x, uint4* __restrict__ xb, int nx8,
                      const int* __restrict__ cind, int* __restrict__ perm) {
    const int t = threadIdx.x;
    if (blockIdx.x == 0) {
        __shared__ int er[64], srb[64], goff[9];
        if (t < 64) er[t] = (cind[t * 32] >> 5) & 7;
        __syncthreads();
        if (t == 0) {
            int cnt[8], off[8];
            for (int e = 0; e < 8; ++e) cnt[e] = 0;
            for (int r = 0; r < 64; ++r) cnt[er[r]]++;
            goff[0] = 0;
            for (int e = 0; e < 8; ++e) { goff[e + 1] = goff[e] + cnt[e]; off[e] = goff[e]; }
            for (int r = 0; r < 64; ++r) srb[off[er[r]]++] = r;
        }
        __syncthreads();
        for (int g = t; g < 1024; g += 256) {
            int e = 0;
            while (g >= goff[e + 1] * 16) ++e;
            const int ne = goff[e + 1] - goff[e];
            const int local = g - goff[e] * 16;
            const int j = local / ne;
            const int idx = local - j * ne;
            perm[g] = srb[goff[e] + idx] * 16 + j;
        }
    }
    const int i = blockIdx.x * 256 + t;
    if (i < nx8) {
        const f32x4v* s = reinterpret_cast<const f32x4v*>(x) + (size_t)i * 2;
        f32x4v v0 = __builtin_nontemporal_load(s);
        f32x4v v1 = __builtin_nontemporal_load(s + 1);
        uint4 w;
        w.x = bfround(v0.x) | (bfround(v0.y) << 16);
        w.y = bfround(v0.z) | (bfround(v0.w) << 16);
        w.z = bfround(v1.x) | (bfround(v1.y) << 16);
        w.w = bfround(v1.z) | (bfround(v1.w) << 16);
        xb[i] = w;
    }
}

// ---------------- main GEMM: 128x256 tile, BK=32; A = pre-cvt bf16 (r12 layout);
// B = fp32 DIRECT from w1 via global_load_lds (no prepass for w1 -> saves ~30us of
// pipeline traffic; fp32 w1 = 128 MB is L3-resident). fp32->bf16 cvt happens in-loop
// on the VALU after ds_read. 80 KB LDS (2 WG/CU), counted vmcnt(10), depth-1 prefetch,
// 4 waves x (64x128), 16x16x32 MFMA, expert-grouped perm, stride-76 epilogue. ----------------
// B LDS layout: row = 32 fp32 = 128 B = 8 x 16B slots; phys_slot = slot ^ (row&7)
// (write via pre-swizzled gld source; read pair p0, p0^1 -> 2-way banks = free).
__global__ __launch_bounds__(256, 2)
void sdd_bf32_kernel(const ushort* __restrict__ xb, const float* __restrict__ w1,
                     const int* __restrict__ rind, const int* __restrict__ cind,
                     const int* __restrict__ perm,
                     float* __restrict__ out) {
    __shared__ ushort sA[2][BLKDIM * BKT];   // 16 KB (bf16, pair-packed swizzled layout)
    __shared__ float  sB[2][256 * BKT];      // 64 KB (fp32, XOR-slot layout)

    int g = blockIdx.x;
    const int nwg = gridDim.x;
    if ((nwg & 7) == 0) {                 // bijective XCD swizzle
        const int cpx = nwg >> 3;
        g = (g & 7) * cpx + (g >> 3);
    }
    g = perm[g];                          // expert-grouped work order
    const int k0 = g * 2;
    const int r  = rind[k0];

    const int t = threadIdx.x;
    const int w = t >> 6;                 // wave 0..3
    const int l = t & 63;

    // ---- A staging (r12-verified inverse map): lane -> (row_in_16, slot4) ----
    const int unx   = (l & 7) ^ ((l >> 3) & 7);
    const int rin16 = 2 * (l >> 3) + (unx >> 2);
    const int kofs  = (unx & 3) * 8;
    const ushort* agb = xb + (size_t)(r * BLKDIM + w * 32 + rin16) * HID + kofs;

    // ---- B staging: wave w covers panel rows w*64..w*64+63 (8 issues of 8 rows) ----
    // lane: r8 = l>>3 (row within 8), s_phys = l&7; pre-swizzled source slot:
    const int slog = (l & 7) ^ (l >> 3);
    const int cblk = cind[k0 + (w >> 1)];
    const float* bgf = w1 + (size_t)(cblk * BLKDIM + (w & 1) * 64 + (l >> 3)) * HID + slog * 4;

    // ---- compute role: 4 waves as 2(M) x 2(blocks), each 64x128 ----
    const int wblk = w & 1;
    const int wr   = (w >> 1) * 64;
    const int lr   = l & 15;
    const int ps_l = (((l >> 4) + ((l & 1) << 2)) ^ (lr >> 1)) * 8;
    const int rhalf = lr >> 1;

    int aoff[4];
#pragma unroll
    for (int m = 0; m < 4; ++m) aoff[m] = ((w >> 1) * 32 + m * 8 + rhalf) * 64 + ps_l;

    // B read: row = wblk*128 + n*16 + lr; slots p0 = (l>>4)*2 ^ (lr&7), p1 = p0^1
    const int p0 = ((l >> 4) * 2) ^ (lr & 7);
    int bo0[8], bo1[8];
#pragma unroll
    for (int n = 0; n < 8; ++n) {
        const int base = (wblk * 128 + n * 16 + lr) * 32;
        bo0[n] = base + p0 * 4;
        bo1[n] = base + (p0 ^ 1) * 4;
    }

    f32x4 acc[4][8];
#pragma unroll
    for (int m = 0; m < 4; ++m)
#pragma unroll
        for (int n = 0; n < 8; ++n)
            acc[m][n] = (f32x4){0.f, 0.f, 0.f, 0.f};

    auto stageA = [&](int b, int kt) {
        gld16(agb + kt * BKT,                    &sA[b][w * 1024]);
        gld16(agb + (size_t)16 * HID + kt * BKT, &sA[b][w * 1024 + 512]);
    };
    auto stageB = [&](int b, int kt) {
#pragma unroll
        for (int i = 0; i < 8; ++i)
            gld16f(bgf + (size_t)(i * 8) * HID + kt * BKT, &sB[b][(w * 64 + i * 8) * 32]);
    };

    // ---- prologue: tiles 0 and 1 (10 issues each) ----
    stageA(0, 0); stageB(0, 0);
    stageA(1, 1); stageB(1, 1);
    asm volatile("s_waitcnt vmcnt(10)" ::: "memory");   // tile 0 resident
    __builtin_amdgcn_s_barrier();
    __builtin_amdgcn_sched_barrier(0);

    for (int kt = 0; kt < NKT; ++kt) {
        const int cur = kt & 1;
        const ushort* sa = sA[cur];
        const float*  sbf = sB[cur];

        // ---- fragment loads (A bf16 direct; B fp32 -> pack to bf16) ----
        short8 aF[4], bF[8];
#pragma unroll
        for (int m = 0; m < 4; ++m)
            aF[m] = *reinterpret_cast<const short8*>(&sa[aoff[m]]);
#pragma unroll
        for (int n = 0; n < 8; ++n) {
            f32x4 lo = *reinterpret_cast<const f32x4*>(&sbf[bo0[n]]);
            f32x4 hi = *reinterpret_cast<const f32x4*>(&sbf[bo1[n]]);
            uint4 u;
            u.x = bfround(lo.x) | (bfround(lo.y) << 16);
            u.y = bfround(lo.z) | (bfround(lo.w) << 16);
            u.z = bfround(hi.x) | (bfround(hi.y) << 16);
            u.w = bfround(hi.z) | (bfround(hi.w) << 16);
            bF[n] = __builtin_bit_cast(short8, u);
        }
        // all LDS reads of buf[cur] retired before anyone overwrites it
        asm volatile("s_waitcnt lgkmcnt(0)" ::: "memory");
        __builtin_amdgcn_sched_barrier(0);
        __builtin_amdgcn_s_barrier();
        __builtin_amdgcn_sched_barrier(0);

        if (kt + 2 < NKT) { stageA(cur, kt + 2); stageB(cur, kt + 2); }

        __builtin_amdgcn_s_setprio(1);
#pragma unroll
        for (int m = 0; m < 4; ++m)
#pragma unroll
            for (int n = 0; n < 8; ++n)
                acc[m][n] = __builtin_amdgcn_mfma_f32_16x16x32_bf16(aF[m], bF[n], acc[m][n], 0, 0, 0);
        __builtin_amdgcn_s_setprio(0);

        if (kt + 1 < NKT) {
            if (kt + 2 < NKT) asm volatile("s_waitcnt vmcnt(10)" ::: "memory");
            else              asm volatile("s_waitcnt vmcnt(0)"  ::: "memory");
        }
        __builtin_amdgcn_s_barrier();
        __builtin_amdgcn_sched_barrier(0);
    }

    // ---- epilogue: per-wave LDS transpose (stride 76), full-line nt float4 stores ----
    float* op = out + (size_t)(k0 + wblk) * (BLKDIM * BLKDIM);
    float* scr = &sB[0][0] + w * 1216;   // 16 x 76 floats per wave (private region)

#pragma unroll
    for (int m = 0; m < 4; ++m)
#pragma unroll
        for (int h = 0; h < 2; ++h) {
#pragma unroll
            for (int n = 0; n < 4; ++n)
#pragma unroll
                for (int j = 0; j < 4; ++j)
                    scr[((l >> 4) * 4 + j) * 76 + n * 16 + lr] = acc[m][h * 4 + n][j];
#pragma unroll
            for (int rg = 0; rg < 4; ++rg) {
                const int tr = rg * 4 + (l >> 4);
                f32x4 v = *reinterpret_cast<const f32x4*>(&scr[tr * 76 + lr * 4]);
                __builtin_nontemporal_store(v,
                    reinterpret_cast<f32x4*>(&op[(size_t)(wr + m * 16 + tr) * BLKDIM
                                                 + h * 64 + lr * 4]));
            }
        }
}

// ---------------- fallback (validated round-1 kernel) ----------------
__device__ __forceinline__ void store16f(ushort* dst, float4 v0, float4 v1, float4 v2, float4 v3) {
    uint4 w0, w1;
    w0.x = bfround(v0.x) | (bfround(v0.y) << 16);
    w0.y = bfround(v0.z) | (bfround(v0.w) << 16);
    w0.z = bfround(v1.x) | (bfround(v1.y) << 16);
    w0.w = bfround(v1.z) | (bfround(v1.w) << 16);
    w1.x = bfround(v2.x) | (bfround(v2.y) << 16);
    w1.y = bfround(v2.z) | (bfround(v2.w) << 16);
    w1.z = bfround(v3.x) | (bfround(v3.y) << 16);
    w1.w = bfround(v3.z) | (bfround(v3.w) << 16);
    uint4* d = reinterpret_cast<uint4*>(dst);
    d[0] = w0; d[1] = w1;
}

__global__ __launch_bounds__(256, 2)
void sdd_bf16_kernel(const float* __restrict__ x, const float* __restrict__ w1,
                     const int* __restrict__ rind, const int* __restrict__ cind,
                     float* __restrict__ out) {
    __shared__ ushort sA[2][BLKDIM * 32];
    __shared__ ushort sB[2][BLKDIM * 32];
    const int k = blockIdx.x;
    const int t = threadIdx.x;
    const int r = rind[k];
    const int c = cind[k];
    const float* Abase = x  + (size_t)r * BLKDIM * HID;
    const float* Bbase = w1 + (size_t)c * BLKDIM * HID;
    const int srow = t >> 1, shalf = t & 1;
    const float* aptr = Abase + (size_t)srow * HID + shalf * 16;
    const float* bptr = Bbase + (size_t)srow * HID + shalf * 16;
    const int soff = srow * 32 + shalf * 16;
    const int wv = t >> 6, lane = t & 63;
    const int wr = (wv >> 1) * 64, wc = (wv & 1) * 64;
    const int lr = lane & 15, lk = (lane >> 4) * 8;
    f32x4 acc[4][4];
#pragma unroll
    for (int m = 0; m < 4; ++m)
#pragma unroll
        for (int n = 0; n < 4; ++n) acc[m][n] = (f32x4){0.f, 0.f, 0.f, 0.f};
    float4 ra[4], rb[4];
#pragma unroll
    for (int i = 0; i < 4; ++i) {
        ra[i] = *reinterpret_cast<const float4*>(aptr + i * 4);
        rb[i] = *reinterpret_cast<const float4*>(bptr + i * 4);
    }
    store16f(&sA[0][soff], ra[0], ra[1], ra[2], ra[3]);
    store16f(&sB[0][soff], rb[0], rb[1], rb[2], rb[3]);
    __syncthreads();
    for (int kt = 0; kt < 32; ++kt) {
        const int cur = kt & 1;
        if (kt + 1 < 32) {
            const float* ap = aptr + (kt + 1) * 32;
            const float* bp = bptr + (kt + 1) * 32;
#pragma unroll
            for (int i = 0; i < 4; ++i) {
                ra[i] = *reinterpret_cast<const float4*>(ap + i * 4);
                rb[i] = *reinterpret_cast<const float4*>(bp + i * 4);
            }
        }
        const ushort* sa = sA[cur];
        const ushort* sb = sB[cur];
        short8 aF[4], bF[4];
#pragma unroll
        for (int m = 0; m < 4; ++m) aF[m] = *reinterpret_cast<const short8*>(&sa[(wr + m * 16 + lr) * 32 + lk]);
#pragma unroll
        for (int n = 0; n < 4; ++n) bF[n] = *reinterpret_cast<const short8*>(&sb[(wc + n * 16 + lr) * 32 + lk]);
#pragma unroll
        for (int m = 0; m < 4; ++m)
#pragma unroll
            for (int n = 0; n < 4; ++n)
                acc[m][n] = __builtin_amdgcn_mfma_f32_16x16x32_bf16(aF[m], bF[n], acc[m][n], 0, 0, 0);
        if (kt + 1 < 32) {
            store16f(&sA[cur ^ 1][soff], ra[0], ra[1], ra[2], ra[3]);
            store16f(&sB[cur ^ 1][soff], rb[0], rb[1], rb[2], rb[3]);
        }
        __syncthreads();
    }
    float* op = out + (size_t)k * (BLKDIM * BLKDIM);
    const int rbase = wr + (lane >> 4) * 4;
#pragma unroll
    for (int m = 0; m < 4; ++m)
#pragma unroll
        for (int n = 0; n < 4; ++n) {
            const int col = wc + n * 16 + lr;
#pragma unroll
            for (int j = 0; j < 4; ++j)
                op[(size_t)(rbase + m * 16 + j) * BLKDIM + col] = acc[m][n][j];
        }
}

extern "C" void kernel_launch(void* const* d_in, const int* in_sizes, int n_in,
                              void* d_out, int out_size, void* d_ws, size_t ws_size,
                              hipStream_t stream) {
    const float* x  = (const float*)d_in[0];
    const float* w1 = (const float*)d_in[1];
    const int* ri   = (const int*)d_in[2];
    const int* ci   = (const int*)d_in[3];
    float* out      = (float*)d_out;
    const int nnz   = in_sizes[2];
    const int nx    = in_sizes[0];
    const int nw    = in_sizes[1];

    const size_t need = (size_t)nx * sizeof(ushort) + 1024 * sizeof(int);
    // Fast path requires the fixed dMoE topology: 64 row-blocks x 32 cols/expert.
    if (ws_size >= need && nnz == 2048 && nx == 8388608 && nw == 33554432) {
        ushort* xb = (ushort*)d_ws;
        int* perm  = (int*)(xb + nx);
        const int nx8 = nx / 8;
        hipLaunchKernelGGL(cvt_sched_kernel, dim3((nx8 + 255) / 256), dim3(256), 0, stream,
                           x, (uint4*)xb, nx8, ci, perm);
        hipLaunchKernelGGL(sdd_bf32_kernel, dim3(nnz / 2), dim3(256), 0, stream,
                           xb, w1, ri, ci, perm, out);
    } else {
        hipLaunchKernelGGL(sdd_bf16_kernel, dim3(nnz), dim3(256), 0, stream,
                           x, w1, ri, ci, out);
    }
}

// Round 18
// 123.450 us; speedup vs baseline: 1.0550x; 1.0550x over previous
//
#include <hip/hip_runtime.h>
#include <hip/hip_bf16.h>
#include <stdint.h>

#define HID 1024
#define BLKDIM 128
#define BKT 32              // K-tile depth
#define NKT (HID / BKT)     // 32 K-tiles
#define NBUF 3              // triple buffer: depth-2 prefetch

using short8 = __attribute__((ext_vector_type(8))) short;
using f32x4  = __attribute__((ext_vector_type(4))) float;
using f32x4v = __attribute__((ext_vector_type(4))) float;

__device__ __forceinline__ uint32_t bfround(float f) {
    uint32_t u = __builtin_bit_cast(uint32_t, f);
    return (u + 0x7FFFu + ((u >> 16) & 1u)) >> 16;   // RNE to bf16
}

__device__ __forceinline__ void gld16(const ushort* g, const ushort* lds_base) {
    __builtin_amdgcn_global_load_lds(
        (const __attribute__((address_space(1))) void*)g,
        (__attribute__((address_space(3))) void*)lds_base, 16, 0, 0);
}

// ---------------- fused pre-pass: fp32->bf16 cvt + schedule build (r12-verified) ----------------
__global__ __launch_bounds__(256)
void cvt_sched_kernel(const float* __restrict__ x, const float* __restrict__ w1,
                      uint4* __restrict__ xb, uint4* __restrict__ wb,
                      int nx8, int nw8,
                      const int* __restrict__ cind, int* __restrict__ perm) {
    const int t = threadIdx.x;
    if (blockIdx.x == 0) {
        __shared__ int er[64], srb[64], goff[9];
        if (t < 64) er[t] = (cind[t * 32] >> 5) & 7;
        __syncthreads();
        if (t == 0) {
            int cnt[8], off[8];
            for (int e = 0; e < 8; ++e) cnt[e] = 0;
            for (int r = 0; r < 64; ++r) cnt[er[r]]++;
            goff[0] = 0;
            for (int e = 0; e < 8; ++e) { goff[e + 1] = goff[e] + cnt[e]; off[e] = goff[e]; }
            for (int r = 0; r < 64; ++r) srb[off[er[r]]++] = r;
        }
        __syncthreads();
        for (int g = t; g < 1024; g += 256) {
            int e = 0;
            while (g >= goff[e + 1] * 16) ++e;
            const int ne = goff[e + 1] - goff[e];
            const int local = g - goff[e] * 16;
            const int j = local / ne;
            const int idx = local - j * ne;
            perm[g] = srb[goff[e] + idx] * 16 + j;
        }
    }
    const int i = blockIdx.x * 256 + t;
    if (i < nx8) {
        const f32x4v* s = reinterpret_cast<const f32x4v*>(x) + (size_t)i * 2;
        f32x4v v0 = __builtin_nontemporal_load(s);
        f32x4v v1 = __builtin_nontemporal_load(s + 1);
        uint4 w;
        w.x = bfround(v0.x) | (bfround(v0.y) << 16);
        w.y = bfround(v0.z) | (bfround(v0.w) << 16);
        w.z = bfround(v1.x) | (bfround(v1.y) << 16);
        w.w = bfround(v1.z) | (bfround(v1.w) << 16);
        xb[i] = w;
    } else if (i < nx8 + nw8) {
        const int j = i - nx8;
        const f32x4v* s = reinterpret_cast<const f32x4v*>(w1) + (size_t)j * 2;
        f32x4v v0 = __builtin_nontemporal_load(s);
        f32x4v v1 = __builtin_nontemporal_load(s + 1);
        uint4 w;
        w.x = bfround(v0.x) | (bfround(v0.y) << 16);
        w.y = bfround(v0.z) | (bfround(v0.w) << 16);
        w.z = bfround(v1.x) | (bfround(v1.y) << 16);
        w.w = bfround(v1.z) | (bfround(v1.w) << 16);
        wb[j] = w;
    }
}

// ---------------- main GEMM (r15-verified, 123.1us total): 128x256 tile, BK=32,
// counted-vmcnt depth-2 pipeline, 4 waves x (64x128), 16x16x32 MFMA,
// expert-grouped perm, 72 KB LDS, stride-76 epilogue, full-line nt stores. ----------------
__global__ __launch_bounds__(256, 2)
void sdd_wide_kernel(const ushort* __restrict__ xb, const ushort* __restrict__ wb,
                     const int* __restrict__ rind, const int* __restrict__ cind,
                     const int* __restrict__ perm,
                     float* __restrict__ out) {
    __shared__ ushort lds[NBUF * BLKDIM * BKT + NBUF * 2 * BLKDIM * BKT];  // 72 KB

    int g = blockIdx.x;
    const int nwg = gridDim.x;
    if ((nwg & 7) == 0) {                 // bijective XCD swizzle
        const int cpx = nwg >> 3;
        g = (g & 7) * cpx + (g >> 3);
    }
    g = perm[g];                          // expert-grouped work order
    const int k0 = g * 2;
    const int r  = rind[k0];

    const int t = threadIdx.x;
    const int w = t >> 6;                 // wave 0..3
    const int l = t & 63;

    ushort* sAb = lds;                            // NBUF x 4096 ushorts
    ushort* sBb = lds + NBUF * BLKDIM * BKT;      // NBUF x 8192 ushorts

    // ---- staging role (r12-verified inverse map): lane -> (row_in_16, slot4) ----
    const int unx   = (l & 7) ^ ((l >> 3) & 7);
    const int rin16 = 2 * (l >> 3) + (unx >> 2);
    const int kofs  = (unx & 3) * 8;

    const ushort* agb = xb + (size_t)(r * BLKDIM + w * 32 + rin16) * HID + kofs;
    const int cblk = cind[k0 + (w >> 1)];
    const ushort* bgb = wb + (size_t)(cblk * BLKDIM + (w & 1) * 64 + rin16) * HID + kofs;

    // ---- compute role: 4 waves as 2(M) x 2(blocks), each 64x128 ----
    const int wr   = (w >> 1) * 64;
    const int wblk = w & 1;
    const int ps_l = (((l >> 4) + ((l & 1) << 2)) ^ ((l & 15) >> 1)) * 8;
    const int rhalf = (l & 15) >> 1;

    int aoff[4], boff[8];
#pragma unroll
    for (int m = 0; m < 4; ++m) aoff[m] = ((w >> 1) * 32 + m * 8 + rhalf) * 64 + ps_l;
#pragma unroll
    for (int n = 0; n < 8; ++n) boff[n] = (wblk * 64 + n * 8 + rhalf) * 64 + ps_l;

    f32x4 acc[4][8];
#pragma unroll
    for (int m = 0; m < 4; ++m)
#pragma unroll
        for (int n = 0; n < 8; ++n)
            acc[m][n] = (f32x4){0.f, 0.f, 0.f, 0.f};

    auto stage = [&](int b, int kt) {
        gld16(agb + kt * BKT,                          &sAb[b * 4096 + w * 1024]);
        gld16(agb + (size_t)16 * HID + kt * BKT,       &sAb[b * 4096 + w * 1024 + 512]);
        gld16(bgb + kt * BKT,                          &sBb[b * 8192 + w * 2048]);
        gld16(bgb + (size_t)16 * HID + kt * BKT,       &sBb[b * 8192 + w * 2048 + 512]);
        gld16(bgb + (size_t)32 * HID + kt * BKT,       &sBb[b * 8192 + w * 2048 + 1024]);
        gld16(bgb + (size_t)48 * HID + kt * BKT,       &sBb[b * 8192 + w * 2048 + 1536]);
    };

    stage(0, 0);
    stage(1, 1);
    asm volatile("s_waitcnt vmcnt(6)" ::: "memory");   // tile 0 resident
    __builtin_amdgcn_s_barrier();
    __builtin_amdgcn_sched_barrier(0);

    for (int kt = 0; kt < NKT; ++kt) {
        const int cur = kt % 3;
        const int nxt = (kt + 2) % 3;
        const bool pre = (kt + 2) < NKT;
        const ushort* sa = &sAb[cur * 4096];
        const ushort* sb = &sBb[cur * 8192];

        short8 aF[4], bF[8];
#pragma unroll
        for (int m = 0; m < 4; ++m)
            aF[m] = *reinterpret_cast<const short8*>(&sa[aoff[m]]);
#pragma unroll
        for (int n = 0; n < 8; ++n)
            bF[n] = *reinterpret_cast<const short8*>(&sb[boff[n]]);
        if (pre) stage(nxt, kt + 2);
        __builtin_amdgcn_s_setprio(1);
#pragma unroll
        for (int m = 0; m < 4; ++m)
#pragma unroll
            for (int n = 0; n < 8; ++n)
                acc[m][n] = __builtin_amdgcn_mfma_f32_16x16x32_bf16(aF[m], bF[n], acc[m][n], 0, 0, 0);
        __builtin_amdgcn_s_setprio(0);

        if (pre) asm volatile("s_waitcnt vmcnt(6)" ::: "memory");
        else     asm volatile("s_waitcnt vmcnt(0)" ::: "memory");
        __builtin_amdgcn_s_barrier();
        __builtin_amdgcn_sched_barrier(0);
    }

    // ---- epilogue: per-wave LDS transpose (stride 76), full-line nt float4 stores ----
    float* op = out + (size_t)(k0 + wblk) * (BLKDIM * BLKDIM);
    float* scr = reinterpret_cast<float*>(lds) + w * 1216;   // 16 x 76 floats per wave

#pragma unroll
    for (int m = 0; m < 4; ++m)
#pragma unroll
        for (int h = 0; h < 2; ++h) {
#pragma unroll
            for (int n = 0; n < 4; ++n)
#pragma unroll
                for (int j = 0; j < 4; ++j)
                    scr[((l >> 4) * 4 + j) * 76 + n * 16 + (l & 15)] = acc[m][h * 4 + n][j];
#pragma unroll
            for (int rg = 0; rg < 4; ++rg) {
                const int tr = rg * 4 + (l >> 4);
                f32x4 v = *reinterpret_cast<const f32x4*>(&scr[tr * 76 + (l & 15) * 4]);
                __builtin_nontemporal_store(v,
                    reinterpret_cast<f32x4*>(&op[(size_t)(wr + m * 16 + tr) * BLKDIM
                                                 + h * 64 + (l & 15) * 4]));
            }
        }
}

// ---------------- fallback (validated round-1 kernel) ----------------
__device__ __forceinline__ void store16f(ushort* dst, float4 v0, float4 v1, float4 v2, float4 v3) {
    uint4 w0, w1;
    w0.x = bfround(v0.x) | (bfround(v0.y) << 16);
    w0.y = bfround(v0.z) | (bfround(v0.w) << 16);
    w0.z = bfround(v1.x) | (bfround(v1.y) << 16);
    w0.w = bfround(v1.z) | (bfround(v1.w) << 16);
    w1.x = bfround(v2.x) | (bfround(v2.y) << 16);
    w1.y = bfround(v2.z) | (bfround(v2.w) << 16);
    w1.z = bfround(v3.x) | (bfround(v3.y) << 16);
    w1.w = bfround(v3.z) | (bfround(v3.w) << 16);
    uint4* d = reinterpret_cast<uint4*>(dst);
    d[0] = w0; d[1] = w1;
}

__global__ __launch_bounds__(256, 2)
void sdd_bf16_kernel(const float* __restrict__ x, const float* __restrict__ w1,
                     const int* __restrict__ rind, const int* __restrict__ cind,
                     float* __restrict__ out) {
    __shared__ ushort sA[2][BLKDIM * 32];
    __shared__ ushort sB[2][BLKDIM * 32];
    const int k = blockIdx.x;
    const int t = threadIdx.x;
    const int r = rind[k];
    const int c = cind[k];
    const float* Abase = x  + (size_t)r * BLKDIM * HID;
    const float* Bbase = w1 + (size_t)c * BLKDIM * HID;
    const int srow = t >> 1, shalf = t & 1;
    const float* aptr = Abase + (size_t)srow * HID + shalf * 16;
    const float* bptr = Bbase + (size_t)srow * HID + shalf * 16;
    const int soff = srow * 32 + shalf * 16;
    const int wv = t >> 6, lane = t & 63;
    const int wr = (wv >> 1) * 64, wc = (wv & 1) * 64;
    const int lr = lane & 15, lk = (lane >> 4) * 8;
    f32x4 acc[4][4];
#pragma unroll
    for (int m = 0; m < 4; ++m)
#pragma unroll
        for (int n = 0; n < 4; ++n) acc[m][n] = (f32x4){0.f, 0.f, 0.f, 0.f};
    float4 ra[4], rb[4];
#pragma unroll
    for (int i = 0; i < 4; ++i) {
        ra[i] = *reinterpret_cast<const float4*>(aptr + i * 4);
        rb[i] = *reinterpret_cast<const float4*>(bptr + i * 4);
    }
    store16f(&sA[0][soff], ra[0], ra[1], ra[2], ra[3]);
    store16f(&sB[0][soff], rb[0], rb[1], rb[2], rb[3]);
    __syncthreads();
    for (int kt = 0; kt < 32; ++kt) {
        const int cur = kt & 1;
        if (kt + 1 < 32) {
            const float* ap = aptr + (kt + 1) * 32;
            const float* bp = bptr + (kt + 1) * 32;
#pragma unroll
            for (int i = 0; i < 4; ++i) {
                ra[i] = *reinterpret_cast<const float4*>(ap + i * 4);
                rb[i] = *reinterpret_cast<const float4*>(bp + i * 4);
            }
        }
        const ushort* sa = sA[cur];
        const ushort* sb = sB[cur];
        short8 aF[4], bF[4];
#pragma unroll
        for (int m = 0; m < 4; ++m) aF[m] = *reinterpret_cast<const short8*>(&sa[(wr + m * 16 + lr) * 32 + lk]);
#pragma unroll
        for (int n = 0; n < 4; ++n) bF[n] = *reinterpret_cast<const short8*>(&sb[(wc + n * 16 + lr) * 32 + lk]);
#pragma unroll
        for (int m = 0; m < 4; ++m)
#pragma unroll
            for (int n = 0; n < 4; ++n)
                acc[m][n] = __builtin_amdgcn_mfma_f32_16x16x32_bf16(aF[m], bF[n], acc[m][n], 0, 0, 0);
        if (kt + 1 < 32) {
            store16f(&sA[cur ^ 1][soff], ra[0], ra[1], ra[2], ra[3]);
            store16f(&sB[cur ^ 1][soff], rb[0], rb[1], rb[2], rb[3]);
        }
        __syncthreads();
    }
    float* op = out + (size_t)k * (BLKDIM * BLKDIM);
    const int rbase = wr + (lane >> 4) * 4;
#pragma unroll
    for (int m = 0; m < 4; ++m)
#pragma unroll
        for (int n = 0; n < 4; ++n) {
            const int col = wc + n * 16 + lr;
#pragma unroll
            for (int j = 0; j < 4; ++j)
                op[(size_t)(rbase + m * 16 + j) * BLKDIM + col] = acc[m][n][j];
        }
}

extern "C" void kernel_launch(void* const* d_in, const int* in_sizes, int n_in,
                              void* d_out, int out_size, void* d_ws, size_t ws_size,
                              hipStream_t stream) {
    const float* x  = (const float*)d_in[0];
    const float* w1 = (const float*)d_in[1];
    const int* ri   = (const int*)d_in[2];
    const int* ci   = (const int*)d_in[3];
    float* out      = (float*)d_out;
    const int nnz   = in_sizes[2];
    const int nx    = in_sizes[0];
    const int nw    = in_sizes[1];

    const size_t need = ((size_t)nx + (size_t)nw) * sizeof(ushort) + 4096 * sizeof(int);
    // Fast path requires the fixed dMoE topology: 64 row-blocks x 32 cols/expert.
    if (ws_size >= need && nnz == 2048 && nx == 8388608 && nw == 33554432) {
        ushort* xb = (ushort*)d_ws;
        ushort* wb = xb + nx;
        int* perm  = (int*)(wb + nw);
        const int nx8 = nx / 8, nw8 = nw / 8;
        const int ncvt = (nx8 + nw8 + 255) / 256;
        hipLaunchKernelGGL(cvt_sched_kernel, dim3(ncvt), dim3(256), 0, stream,
                           x, w1, (uint4*)xb, (uint4*)wb, nx8, nw8, ci, perm);
        hipLaunchKernelGGL(sdd_wide_kernel, dim3(nnz / 2), dim3(256), 0, stream,
                           xb, wb, ri, ci, perm, out);
    } else {
        hipLaunchKernelGGL(sdd_bf16_kernel, dim3(nnz), dim3(256), 0, stream,
                           x, w1, ri, ci, out);
    }
}